// Round 2
// baseline (331.101 us; speedup 1.0000x reference)
//
#include <hip/hip_runtime.h>
#include <hip/hip_bf16.h>

#define T_TOK 16384
#define HDIM  4096
#define NEXP  64
#define BM    64
#define BK    64

// ---------------------------------------------------------------------------
// Kernel A: logits[t][e] = sum_h x[t][h] * w[e][h], accumulated in FP64 so
// the expert ordering matches the high-precision numpy reference.
// 256 threads/block, tile = 64 tokens x 64 experts, BK=64 k-chunk in LDS.
// Thread (tg = tid/16, eg = tid%16) owns tokens {tg+16i} x experts {eg+16j}.
// LDS stores fp64 (converted once at staging). Layout in 16B double2 units:
// physical unit = (logical unit) ^ (row & 7)  -> X-reads conflict-free,
// W-reads 2-way (free).
// ---------------------------------------------------------------------------
__global__ __launch_bounds__(256, 2)
void gate_gemm_f64(const float* __restrict__ x, const float* __restrict__ w,
                   double* __restrict__ logits, int ksplit) {
    const int kb = blockIdx.x % ksplit;   // K-split slice
    const int mb = blockIdx.x / ksplit;   // token tile
    const int t0 = mb * BM;
    const int kspan = HDIM / ksplit;
    const int k_begin = kb * kspan;
    const int k_end   = k_begin + kspan;

    __shared__ double Xs[BM * BK];
    __shared__ double Ws[NEXP * BK];

    const int tid = threadIdx.x;
    const int tg  = tid >> 4;   // 0..15 token group
    const int eg  = tid & 15;   // 0..15 expert group

    double acc[4][4];
#pragma unroll
    for (int i = 0; i < 4; ++i)
#pragma unroll
        for (int j = 0; j < 4; ++j) acc[i][j] = 0.0;

    for (int kc = k_begin; kc < k_end; kc += BK) {
        __syncthreads();
        // stage: each thread loads 4 float4 per matrix, converts to fp64,
        // writes two double2 units per float4 (swizzled).
#pragma unroll
        for (int i = 0; i < 4; ++i) {
            const int L  = tid + 256 * i;    // 0..1023
            const int r  = L >> 4;           // row (token or expert) 0..63
            const int k4 = L & 15;           // float4 index along k
            const int s  = r & 7;
            const int u0 = (2 * k4) ^ s;
            const int u1 = (2 * k4 + 1) ^ s;
            const float4 xv = *(const float4*)(x + (size_t)(t0 + r) * HDIM + kc + 4 * k4);
            ((double2*)Xs)[r * 32 + u0] = make_double2((double)xv.x, (double)xv.y);
            ((double2*)Xs)[r * 32 + u1] = make_double2((double)xv.z, (double)xv.w);
            const float4 wv = *(const float4*)(w + (size_t)r * HDIM + kc + 4 * k4);
            ((double2*)Ws)[r * 32 + u0] = make_double2((double)wv.x, (double)wv.y);
            ((double2*)Ws)[r * 32 + u1] = make_double2((double)wv.z, (double)wv.w);
        }
        __syncthreads();

#pragma unroll
        for (int k4 = 0; k4 < 16; ++k4) {
            double xd[4][4], wd[4][4];
#pragma unroll
            for (int i = 0; i < 4; ++i) {
                const int t  = tg + 16 * i;
                const int st = t & 7;
                const double2 a = ((const double2*)Xs)[t * 32 + ((2 * k4) ^ st)];
                const double2 b = ((const double2*)Xs)[t * 32 + ((2 * k4 + 1) ^ st)];
                xd[i][0] = a.x; xd[i][1] = a.y; xd[i][2] = b.x; xd[i][3] = b.y;
                const int e  = eg + 16 * i;
                const int se = e & 7;
                const double2 c = ((const double2*)Ws)[e * 32 + ((2 * k4) ^ se)];
                const double2 d = ((const double2*)Ws)[e * 32 + ((2 * k4 + 1) ^ se)];
                wd[i][0] = c.x; wd[i][1] = c.y; wd[i][2] = d.x; wd[i][3] = d.y;
            }
#pragma unroll
            for (int i = 0; i < 4; ++i)
#pragma unroll
                for (int j = 0; j < 4; ++j)
#pragma unroll
                    for (int d0 = 0; d0 < 4; ++d0)
                        acc[i][j] = fma(xd[i][d0], wd[j][d0], acc[i][j]);
        }
    }

    double* outp = logits + (size_t)kb * T_TOK * NEXP;
#pragma unroll
    for (int i = 0; i < 4; ++i)
#pragma unroll
        for (int j = 0; j < 4; ++j) {
            const int t = t0 + tg + 16 * i;
            const int e = eg + 16 * j;
            outp[(size_t)t * NEXP + e] = acc[i][j];
        }
}

// ---------------------------------------------------------------------------
// Kernel B: per-token top-16 selection on FP64 logits (softmax is monotone,
// so ranking by logits == ranking by gates). Weights computed in fp32 as
// exp(l - m) / sum_top8 exp(l_j - m) — the softmax denominator cancels.
// One 64-lane wave per token; 4 waves (256 thr) per block.
// Outputs (all stored as float32, concatenated):
//   [0]          expert_weight    (T,8)
//   [T*8]        expert_index     (T,8)
//   [2*T*8]      cpu_expert_index (T,8) = ranks 8..15
//   [3*T*8]      indices_all      (T,8) = ranks 0..7
// ---------------------------------------------------------------------------
__global__ __launch_bounds__(256)
void gate_topk_f64(const double* __restrict__ logits, int ksplit,
                   float* __restrict__ out) {
    const int wave = threadIdx.x >> 6;
    const int lane = threadIdx.x & 63;
    const int t = blockIdx.x * 4 + wave;
    if (t >= T_TOK) return;

    double l = logits[(size_t)t * NEXP + lane];
    if (ksplit == 2) l += logits[(size_t)T_TOK * NEXP + (size_t)t * NEXP + lane];

    // wave max of logits (for stable exp later)
    double m = l;
#pragma unroll
    for (int s = 1; s < 64; s <<= 1) m = fmax(m, __shfl_xor(m, s));

    // iterative top-16: wave argmax with (value desc, index asc) tie-break
    double v = l;
    const int idx = lane;
    double mylog = 0.0;
    int    myidx = 0;
#pragma unroll
    for (int r = 0; r < 16; ++r) {
        double bv = v;
        int    bi = idx;
#pragma unroll
        for (int s = 1; s < 64; s <<= 1) {
            const double ov = __shfl_xor(bv, s);
            const int    oi = __shfl_xor(bi, s);
            if (ov > bv || (ov == bv && oi < bi)) { bv = ov; bi = oi; }
        }
        if (lane == r) { mylog = bv; myidx = bi; }
        if (idx == bi) v = -1.0e308;   // exclude selected expert
    }

    // fp32 gate numerators for the selected ranks
    const float p = (lane < 16) ? expf((float)(mylog - m)) : 0.f;
    float s8 = (lane < 8) ? p : 0.f;
#pragma unroll
    for (int s = 1; s < 64; s <<= 1) s8 += __shfl_xor(s8, s);

    float* ew = out;
    float* ei = out + (size_t)T_TOK * 8;
    float* ci = out + (size_t)2 * T_TOK * 8;
    float* ia = out + (size_t)3 * T_TOK * 8;
    if (lane < 8) {
        ew[(size_t)t * 8 + lane] = p / s8;   // s8 >= 1 (rank0 contributes 1)
        ei[(size_t)t * 8 + lane] = (float)myidx;
        ia[(size_t)t * 8 + lane] = (float)myidx;
    } else if (lane < 16) {
        ci[(size_t)t * 8 + (lane - 8)] = (float)myidx;
    }
}

extern "C" void kernel_launch(void* const* d_in, const int* in_sizes, int n_in,
                              void* d_out, int out_size, void* d_ws, size_t ws_size,
                              hipStream_t stream) {
    const float* x = (const float*)d_in[0];
    const float* w = (const float*)d_in[1];
    float* out     = (float*)d_out;
    double* logits = (double*)d_ws;

    const size_t need2 = (size_t)2 * T_TOK * NEXP * sizeof(double);
    const int ksplit = (ws_size >= need2) ? 2 : 1;

    dim3 blockA(256), gridA((T_TOK / BM) * ksplit);
    gate_gemm_f64<<<gridA, blockA, 0, stream>>>(x, w, logits, ksplit);

    dim3 blockB(256), gridB(T_TOK / 4);
    gate_topk_f64<<<gridB, blockB, 0, stream>>>(logits, ksplit, out);
}